// Round 8
// baseline (449.494 us; speedup 1.0000x reference)
//
#include <hip/hip_runtime.h>
#include <cstdint>

constexpr int BTOT  = 1048576;
constexpr int LCLS  = 81;
constexpr int GRP   = 9;
constexpr int ROWS  = 128;                   // rows per block (one wave, 2 rows/lane)
constexpr int THR   = 64;
constexpr int NBLK  = BTOT / ROWS;           // 8192
constexpr int TILEF = ROWS * LCLS;           // 10368 floats = 41,472 B
constexpr int TILE4 = TILEF / 4;             // 2592 float4
constexpr int FULLR = TILE4 / THR;           // 40 full DMA rounds
constexpr int TAIL  = TILE4 - FULLR * THR;   // 32 leftover float4 (lanes < 32)
constexpr int OPS1  = 21;                    // phase-1 ops: floats 0..5375 -> rows 0..66
constexpr float FIX = 67108864.0f;           // 2^26 fixed-point loss scale

// Async global->LDS, 16B per lane, no VGPR round-trip (m97 pattern).
__device__ __forceinline__ void gload_lds16(const float* gsrc, float* ldst) {
    __builtin_amdgcn_global_load_lds(
        (const __attribute__((address_space(1))) void*)gsrc,
        (__attribute__((address_space(3))) void*)ldst,
        16, 0, 0);
}

// Rare knife-edge path (~1e-5 of rows): group argmax in f64 from global row.
__device__ __attribute__((noinline)) int refine_group_f64(const float* __restrict__ xrow)
{
    double best = -1.0; int bi = 0;
    #pragma unroll
    for (int g = 0; g < GRP; ++g) {
        double s = 0.0;
        #pragma unroll
        for (int j = 0; j < GRP; ++j) s += exp((double)xrow[g * GRP + j]);
        if (s > best) { best = s; bi = g; }
    }
    return bi;
}

// Validated compute core (R4/R5): one row from LDS -> pred/loss/dist contribs.
__device__ __forceinline__ void do_row(
    const float* __restrict__ xr,      // LDS row base
    const float* __restrict__ xg,      // global row base (refine only)
    int t, float* __restrict__ outp,
    unsigned long long& lq, unsigned& dT)
{
    float gs[GRP];
    #pragma unroll
    for (int g = 0; g < GRP; ++g) {
        float s = 0.0f;
        #pragma unroll
        for (int j = 0; j < GRP; ++j) s += __expf(xr[g * GRP + j]);
        gs[g] = s;
    }
    float S = gs[0];
    #pragma unroll
    for (int g = 1; g < GRP; ++g) S += gs[g];

    float g1 = gs[0], g2 = -1e30f; int gi = 0;
    #pragma unroll
    for (int g = 1; g < GRP; ++g) {
        const float v = gs[g];
        const bool gt2 = v > g1;
        g2 = gt2 ? g1 : (v > g2 ? v : g2);
        g1 = gt2 ? v  : g1;
        gi = gt2 ? g  : gi;
    }

    const int parent = t / GRP;
    float gpar = gs[0];
    #pragma unroll
    for (int g = 1; g < GRP; ++g)
        gpar = (parent == g) ? gs[g] : gpar;       // static-index select chain

    if (g1 - g2 < 1e-5f * g1) gi = refine_group_f64(xg);

    // within-group argmax on RAW x — exp/softmax monotonic, so EXACT
    const int wb = gi * GRP;
    float w1 = xr[wb]; int wi = 0;
    #pragma unroll
    for (int j = 1; j < GRP; ++j) {
        const float v = xr[wb + j];
        if (v > w1) { w1 = v; wi = j; }
    }
    const int pred = gi * GRP + wi;

    const float et  = expf(xr[t]);                 // precise ocml exp, once/row
    const float win = 0.5f * (gpar + et) / S;
    const float nl  = -logf(win);
    lq += (unsigned long long)llrintf(nl * FIX);
    dT += (pred == t) ? 0u : ((gi == parent) ? 1u : 2u);

    *outp = (float)pred;
}

__global__ __launch_bounds__(THR) void hl_main(
    const float* __restrict__ x, const int* __restrict__ tgt,
    float* __restrict__ out, unsigned long long* __restrict__ acc)
{
    __shared__ float tile[TILEF];                // 41,472 B -> 3 blocks/CU
    const int lane = threadIdx.x;
    const int blk  = blockIdx.x;
    const size_t tbase = (size_t)blk * TILEF;
    const float* gt = x + tbase;

    // targets first (retire with phase-1 wait)
    const int rowA = blk * ROWS + lane;          // rows 0..63 of tile
    const int rowB = rowA + 64;                  // rows 64..127
    const int tA = tgt[rowA];                    // VMEM op 1
    const int tB = tgt[rowB];                    // VMEM op 2

    // issue the whole tile: 40 full ops + tail (lanes<32) = 41 ops
    #pragma unroll
    for (int r = 0; r < FULLR; ++r) {
        const int i = r * THR + lane;
        gload_lds16(gt + 4 * i, &tile[4 * i]);
    }
    if (lane < TAIL) {
        const int i = FULLR * THR + lane;
        gload_lds16(gt + 4 * i, &tile[4 * i]);
    }

    unsigned long long lq = 0;
    unsigned dT = 0;

    // phase 1: newest 20 outstanding = stage ops 21..40; retires tgt + ops 0..20
    // (floats 0..5375 -> rows 0..66 resident; we need rows 0..63)
    asm volatile("s_waitcnt vmcnt(20)" ::: "memory");
    __builtin_amdgcn_sched_barrier(0);
    do_row(tile + lane * LCLS, x + tbase + (size_t)lane * LCLS,
           tA, out + 1 + rowA, lq, dT);          // + 1 store (newest VMEM)

    // phase 2: leave only the pred-store in flight; rows 64..127 now resident
    asm volatile("s_waitcnt vmcnt(1)" ::: "memory");
    __builtin_amdgcn_sched_barrier(0);
    do_row(tile + (64 + lane) * LCLS, x + tbase + (size_t)(64 + lane) * LCLS,
           tB, out + 1 + rowB, lq, dT);

    // ---- deterministic wave reduction + order-independent integer atomics ----
    #pragma unroll
    for (int off = 32; off > 0; off >>= 1) {
        lq += __shfl_down(lq, off);
        dT += __shfl_down(dT, off);
    }
    if (lane == 0) {
        atomicAdd(&acc[0], lq);
        atomicAdd(&acc[1], (unsigned long long)dT);
        __threadfence();
        unsigned* tick = (unsigned*)(acc + 2);
        const unsigned old = atomicAdd(tick, 1u);
        if (old == (unsigned)(NBLK - 1)) {       // last block finalizes
            __threadfence();
            const unsigned long long ta = atomicAdd(&acc[0], 0ull);
            const unsigned long long tb = atomicAdd(&acc[1], 0ull);
            out[0] = (float)(((double)ta / 67108864.0) / (double)BTOT);
            out[1 + BTOT] = (float)tb;
        }
    }
}

extern "C" void kernel_launch(void* const* d_in, const int* in_sizes, int n_in,
                              void* d_out, int out_size, void* d_ws, size_t ws_size,
                              hipStream_t stream) {
    const float* outputs = (const float*)d_in[0];
    const int*   target  = (const int*)d_in[1];
    float* out = (float*)d_out;
    unsigned long long* acc = (unsigned long long*)d_ws;  // [loss_q, dist, ticket] = 24 B

    hipMemsetAsync(d_ws, 0, 24, stream);                  // re-zero accumulators per call
    hl_main<<<NBLK, THR, 0, stream>>>(outputs, target, out, acc);
}

// Round 9
// 80.021 us; speedup vs baseline: 5.6172x; 5.6172x over previous
//
#include <hip/hip_runtime.h>
#include <cstdint>

constexpr int BTOT  = 1048576;
constexpr int LCLS  = 81;
constexpr int GRP   = 9;
constexpr int ROWS  = 128;                   // rows per block (one wave, 2 rows/lane)
constexpr int THR   = 64;
constexpr int NBLK  = BTOT / ROWS;           // 8192
constexpr int TILEF = ROWS * LCLS;           // 10368 floats = 41,472 B
constexpr int TILE4 = TILEF / 4;             // 2592 float4
constexpr int FULLR = TILE4 / THR;           // 40 full DMA rounds
constexpr int TAIL  = TILE4 - FULLR * THR;   // 32 leftover float4 (lanes < 32)
constexpr float FIX = 67108864.0f;           // 2^26 fixed-point loss scale

// Async global->LDS, 16B per lane, no VGPR round-trip (m97 pattern).
__device__ __forceinline__ void gload_lds16(const float* gsrc, float* ldst) {
    __builtin_amdgcn_global_load_lds(
        (const __attribute__((address_space(1))) void*)gsrc,
        (__attribute__((address_space(3))) void*)ldst,
        16, 0, 0);
}

// Rare knife-edge path (~1e-5 of rows): group argmax in f64 from global row.
__device__ __attribute__((noinline)) int refine_group_f64(const float* __restrict__ xrow)
{
    double best = -1.0; int bi = 0;
    #pragma unroll
    for (int g = 0; g < GRP; ++g) {
        double s = 0.0;
        #pragma unroll
        for (int j = 0; j < GRP; ++j) s += exp((double)xrow[g * GRP + j]);
        if (s > best) { best = s; bi = g; }
    }
    return bi;
}

// Validated compute core (R4/R5/R8): one row from LDS -> pred/loss/dist.
__device__ __forceinline__ void do_row(
    const float* __restrict__ xr,      // LDS row base
    const float* __restrict__ xg,      // global row base (refine only)
    int t, float* __restrict__ outp,
    unsigned long long& lq, unsigned& dT)
{
    float gs[GRP];
    #pragma unroll
    for (int g = 0; g < GRP; ++g) {
        float s = 0.0f;
        #pragma unroll
        for (int j = 0; j < GRP; ++j) s += __expf(xr[g * GRP + j]);
        gs[g] = s;
    }
    float S = gs[0];
    #pragma unroll
    for (int g = 1; g < GRP; ++g) S += gs[g];

    float g1 = gs[0], g2 = -1e30f; int gi = 0;
    #pragma unroll
    for (int g = 1; g < GRP; ++g) {
        const float v = gs[g];
        const bool gt2 = v > g1;
        g2 = gt2 ? g1 : (v > g2 ? v : g2);
        g1 = gt2 ? v  : g1;
        gi = gt2 ? g  : gi;
    }

    const int parent = t / GRP;
    float gpar = gs[0];
    #pragma unroll
    for (int g = 1; g < GRP; ++g)
        gpar = (parent == g) ? gs[g] : gpar;       // static-index select chain

    if (g1 - g2 < 1e-5f * g1) gi = refine_group_f64(xg);

    // within-group argmax on RAW x — exp/softmax monotonic, so EXACT
    const int wb = gi * GRP;
    float w1 = xr[wb]; int wi = 0;
    #pragma unroll
    for (int j = 1; j < GRP; ++j) {
        const float v = xr[wb + j];
        if (v > w1) { w1 = v; wi = j; }
    }
    const int pred = gi * GRP + wi;

    const float et  = expf(xr[t]);                 // precise ocml exp, once/row
    const float win = 0.5f * (gpar + et) / S;
    const float nl  = -logf(win);
    lq += (unsigned long long)llrintf(nl * FIX);
    dT += (pred == t) ? 0u : ((gi == parent) ? 1u : 2u);

    *outp = (float)pred;
}

__global__ __launch_bounds__(THR) void hl_main(
    const float* __restrict__ x, const int* __restrict__ tgt,
    float* __restrict__ out, unsigned long long* __restrict__ part)
{
    __shared__ float tile[TILEF];                // 41,472 B -> 3 blocks/CU
    const int lane = threadIdx.x;
    const int blk  = blockIdx.x;
    const size_t tbase = (size_t)blk * TILEF;
    const float* gt = x + tbase;

    // targets (retire with the phase-1 wait regardless of issue order)
    const int rowA = blk * ROWS + lane;          // rows 0..63 of tile
    const int rowB = rowA + 64;                  // rows 64..127
    const int tA = tgt[rowA];                    // VMEM op
    const int tB = tgt[rowB];                    // VMEM op

    // issue the whole tile: 40 full ops + tail (lanes<32) = 41 DMA ops
    #pragma unroll
    for (int r = 0; r < FULLR; ++r) {
        const int i = r * THR + lane;
        gload_lds16(gt + 4 * i, &tile[4 * i]);
    }
    if (lane < TAIL) {
        const int i = FULLR * THR + lane;
        gload_lds16(gt + 4 * i, &tile[4 * i]);
    }

    unsigned long long lq = 0;
    unsigned dT = 0;

    // phase 1: 43 VMEM ops outstanding; retire 23 oldest -> covers stage ops
    // 0..20 (floats 0..5375 -> rows 0..66 resident) in ANY tgt/stage order.
    asm volatile("s_waitcnt vmcnt(20)" ::: "memory");
    __builtin_amdgcn_sched_barrier(0);
    do_row(tile + lane * LCLS, x + tbase + (size_t)lane * LCLS,
           tA, out + 1 + rowA, lq, dT);          // + 1 store (newest VMEM)

    // phase 2: leave only the pred-store in flight; rows 64..127 resident
    asm volatile("s_waitcnt vmcnt(1)" ::: "memory");
    __builtin_amdgcn_sched_barrier(0);
    do_row(tile + (64 + lane) * LCLS, x + tbase + (size_t)(64 + lane) * LCLS,
           tB, out + 1 + rowB, lq, dT);

    // ---- deterministic single-wave reduction -> per-block partials ----
    #pragma unroll
    for (int off = 32; off > 0; off >>= 1) {
        lq += __shfl_down(lq, off);
        dT += __shfl_down(dT, off);
    }
    if (lane == 0) {
        part[blk] = lq;
        part[NBLK + blk] = (unsigned long long)dT;
    }
}

__global__ __launch_bounds__(1024) void hl_final(
    const unsigned long long* __restrict__ part, float* __restrict__ out)
{
    const int tid = threadIdx.x;
    unsigned long long a = 0, b = 0;
    for (int i = tid; i < NBLK; i += 1024) { a += part[i]; b += part[NBLK + i]; }
    #pragma unroll
    for (int off = 32; off > 0; off >>= 1) { a += __shfl_down(a, off); b += __shfl_down(b, off); }
    __shared__ unsigned long long rA[16], rB[16];
    if ((tid & 63) == 0) { rA[tid >> 6] = a; rB[tid >> 6] = b; }
    __syncthreads();
    if (tid == 0) {
        unsigned long long ta = 0, tb = 0;
        #pragma unroll
        for (int w = 0; w < 16; ++w) { ta += rA[w]; tb += rB[w]; }
        const double loss = ((double)ta / 67108864.0) / (double)BTOT;
        out[0] = (float)loss;                  // -mean(log(win))
        out[1 + BTOT] = (float)tb;             // total_dist
    }
}

extern "C" void kernel_launch(void* const* d_in, const int* in_sizes, int n_in,
                              void* d_out, int out_size, void* d_ws, size_t ws_size,
                              hipStream_t stream) {
    const float* outputs = (const float*)d_in[0];
    const int*   target  = (const int*)d_in[1];
    float* out = (float*)d_out;
    unsigned long long* part = (unsigned long long*)d_ws;   // needs 2*8192*8 = 131,072 B

    hl_main<<<NBLK, THR, 0, stream>>>(outputs, target, out, part);
    hl_final<<<1, 1024, 0, stream>>>(part, out);
}